// Round 1
// baseline (233.324 us; speedup 1.0000x reference)
//
#include <hip/hip_runtime.h>

#define LN_EPS 1e-5f

// ---------------------------------------------------------------------------
// Stage kernel: [optional LN(prev stats) + optional 2x2 maxpool] -> locally-
// connected conv (per-position weights) + bias + ReLU -> write raw output +
// accumulate per-sample (sum, sumsq) for this stage's LayerNorm.
//
// Block = TILE x TILE output tile  x  all 64 samples. 256 threads =
// 4 position-groups x 64 samples (lane = sample).
// ---------------------------------------------------------------------------
template<int RIN, bool POOL, bool FIRST, int K, int TILE>
__launch_bounds__(256)
__global__ void lc_stage(const float* __restrict__ in,      // raw prev activations (or x)
                         const float* __restrict__ pstats,  // prev [sum(64), sumsq(64)]
                         const float* __restrict__ gamma,   // prev LN gamma [RIN*RIN]
                         const float* __restrict__ beta,    // prev LN beta  [RIN*RIN]
                         const float* __restrict__ w,       // [ROUT,ROUT,K,K]
                         const float* __restrict__ bias,    // [ROUT,ROUT]
                         float* __restrict__ out,           // raw this-stage [64,ROUT,ROUT]
                         float* __restrict__ stats)         // this [sum(64), sumsq(64)]
{
    constexpr int CIN  = POOL ? RIN / 2 : RIN;   // conv-input resolution
    constexpr int ROUT = CIN;                    // stride 1, 'same' padding
    constexpr int PAD  = (K - 1) / 2;
    constexpr int RT   = TILE + K - 1;           // staged region side
    constexpr int PP   = RT * RT + 1;            // odd stride -> no bank conflicts
    constexpr int NBLK = ROUT / TILE;
    constexpr int WCNT = TILE * TILE * K * K;
    constexpr float INV_NPREV = 1.0f / (float)(RIN * RIN);

    struct WB { float w[WCNT]; float b[TILE * TILE]; };
    union UU { WB wb; float red[512]; };

    __shared__ float s_in[64 * PP];
    __shared__ UU    s_u;
    __shared__ float s_mean[64], s_rstd[64];

    const int tid = threadIdx.x;
    const int i0  = (blockIdx.x / NBLK) * TILE;
    const int j0  = (blockIdx.x % NBLK) * TILE;

    if constexpr (!FIRST) {
        if (tid < 64) {
            float mu  = pstats[tid] * INV_NPREV;
            float msq = pstats[64 + tid] * INV_NPREV;
            float var = msq - mu * mu;
            s_mean[tid] = mu;
            s_rstd[tid] = 1.0f / sqrtf(var + LN_EPS);
        }
        __syncthreads();
    }

    // --- stage weights + bias into LDS (coalesced; each weight read once) ---
    for (int idx = tid; idx < WCNT; idx += 256) {
        int pi = idx / (K * K);
        int kk = idx % (K * K);
        int gi = i0 + pi / TILE, gj = j0 + pi % TILE;
        s_u.wb.w[idx] = w[(gi * ROUT + gj) * (K * K) + kk];
    }
    if (tid < TILE * TILE) {
        int gi = i0 + tid / TILE, gj = j0 + tid % TILE;
        s_u.wb.b[tid] = bias[gi * ROUT + gj];
    }

    // --- stage input region: normalize (+pool) on the fly ---
    for (int idx = tid; idx < 64 * RT * RT; idx += 256) {
        int s  = idx / (RT * RT);
        int p  = idx % (RT * RT);
        int rr = p / RT, rc = p % RT;
        int ci = i0 - PAD + rr, cj = j0 - PAD + rc;
        float val = 0.0f;
        if (ci >= 0 && ci < CIN && cj >= 0 && cj < CIN) {
            if constexpr (FIRST) {
                val = in[s * RIN * RIN + ci * RIN + cj];
            } else if constexpr (POOL) {
                float mu = s_mean[s], rs = s_rstd[s];
                float best = -3.4e38f;
                #pragma unroll
                for (int dy = 0; dy < 2; dy++) {
                    #pragma unroll
                    for (int dx = 0; dx < 2; dx++) {
                        int ry = 2 * ci + dy, rx = 2 * cj + dx;
                        float raw = in[s * RIN * RIN + ry * RIN + rx];
                        float n = (raw - mu) * rs * gamma[ry * RIN + rx] + beta[ry * RIN + rx];
                        best = fmaxf(best, n);
                    }
                }
                val = best;
            } else {
                float mu = s_mean[s], rs = s_rstd[s];
                float raw = in[s * RIN * RIN + ci * RIN + cj];
                val = (raw - mu) * rs * gamma[ci * RIN + cj] + beta[ci * RIN + cj];
            }
        }
        s_in[s * PP + p] = val;
    }
    __syncthreads();

    // --- compute: lane = sample, group = row subset; sliding-row registers ---
    const int s   = tid & 63;
    const int grp = tid >> 6;
    float lsum = 0.0f, lsq = 0.0f;
    #pragma unroll
    for (int rr = 0; rr < TILE / 4; rr++) {
        const int ti = grp + 4 * rr;
        float acc[TILE];
        #pragma unroll
        for (int tj = 0; tj < TILE; tj++) acc[tj] = s_u.wb.b[ti * TILE + tj];
        #pragma unroll
        for (int ki = 0; ki < K; ki++) {
            float row[RT];
            #pragma unroll
            for (int c = 0; c < RT; c++) row[c] = s_in[s * PP + (ti + ki) * RT + c];
            #pragma unroll
            for (int kj = 0; kj < K; kj++) {
                #pragma unroll
                for (int tj = 0; tj < TILE; tj++)
                    acc[tj] += row[tj + kj] * s_u.wb.w[(ti * TILE + tj) * (K * K) + ki * K + kj];
            }
        }
        #pragma unroll
        for (int tj = 0; tj < TILE; tj++) {
            float v = fmaxf(acc[tj], 0.0f);
            out[s * ROUT * ROUT + (i0 + ti) * ROUT + (j0 + tj)] = v;
            lsum += v;
            lsq  += v * v;
        }
    }

    // --- per-sample LN-stat reduction across the 4 groups, then atomics ---
    __syncthreads();                 // done with s_u.wb, reuse as red
    s_u.red[tid]       = lsum;
    s_u.red[256 + tid] = lsq;
    __syncthreads();
    if (tid < 64) {
        float a = s_u.red[tid] + s_u.red[64 + tid] + s_u.red[128 + tid] + s_u.red[192 + tid];
        float b = s_u.red[256 + tid] + s_u.red[320 + tid] + s_u.red[384 + tid] + s_u.red[448 + tid];
        atomicAdd(&stats[tid], a);
        atomicAdd(&stats[64 + tid], b);
    }
}

// ---------------------------------------------------------------------------
// Final: LN6 -> flatten(256) -> FC(1024) -> softmax. One block per sample.
// ---------------------------------------------------------------------------
__launch_bounds__(256)
__global__ void fc_softmax(const float* __restrict__ t6,     // raw [64,16,16]
                           const float* __restrict__ stats6, // [sum(64), sumsq(64)]
                           const float* __restrict__ g6,
                           const float* __restrict__ be6,
                           const float* __restrict__ fcw,    // [1024,256]
                           const float* __restrict__ fcb,    // [1024]
                           float* __restrict__ out)          // [64,1024]
{
    __shared__ float h[256];
    __shared__ float l[1024];
    __shared__ float red[256];
    const int s   = blockIdx.x;
    const int tid = threadIdx.x;

    float mu  = stats6[s] * (1.0f / 256.0f);
    float msq = stats6[64 + s] * (1.0f / 256.0f);
    float rstd = 1.0f / sqrtf(msq - mu * mu + LN_EPS);
    h[tid] = (t6[s * 256 + tid] - mu) * rstd * g6[tid] + be6[tid];
    __syncthreads();

    float lmax = -3.4e38f;
    #pragma unroll
    for (int r = 0; r < 4; r++) {
        int o = r * 256 + tid;
        const float4* wr = (const float4*)(fcw + o * 256);
        float acc = 0.0f;
        #pragma unroll 8
        for (int k = 0; k < 64; k++) {
            float4 wv = wr[k];
            acc += wv.x * h[4 * k] + wv.y * h[4 * k + 1] + wv.z * h[4 * k + 2] + wv.w * h[4 * k + 3];
        }
        acc += fcb[o];
        l[o] = acc;
        lmax = fmaxf(lmax, acc);
    }
    red[tid] = lmax;
    __syncthreads();
    for (int off = 128; off > 0; off >>= 1) {
        if (tid < off) red[tid] = fmaxf(red[tid], red[tid + off]);
        __syncthreads();
    }
    float M = red[0];
    __syncthreads();

    float lsum = 0.0f;
    #pragma unroll
    for (int r = 0; r < 4; r++) {
        int o = r * 256 + tid;
        float e = expf(l[o] - M);
        l[o] = e;
        lsum += e;
    }
    red[tid] = lsum;
    __syncthreads();
    for (int off = 128; off > 0; off >>= 1) {
        if (tid < off) red[tid] += red[tid + off];
        __syncthreads();
    }
    float inv = 1.0f / red[0];
    #pragma unroll
    for (int r = 0; r < 4; r++) {
        int o = r * 256 + tid;
        out[s * 1024 + o] = l[o] * inv;
    }
}

// ---------------------------------------------------------------------------
extern "C" void kernel_launch(void* const* d_in, const int* in_sizes, int n_in,
                              void* d_out, int out_size, void* d_ws, size_t ws_size,
                              hipStream_t stream) {
    (void)in_sizes; (void)n_in; (void)out_size; (void)ws_size;

    const float* x   = (const float*)d_in[0];
    const float* w1  = (const float*)d_in[1];
    const float* b1  = (const float*)d_in[2];
    const float* g1  = (const float*)d_in[3];
    const float* be1 = (const float*)d_in[4];
    const float* w2  = (const float*)d_in[5];
    const float* b2  = (const float*)d_in[6];
    const float* g2  = (const float*)d_in[7];
    const float* be2 = (const float*)d_in[8];
    const float* w3  = (const float*)d_in[9];
    const float* b3  = (const float*)d_in[10];
    const float* g3  = (const float*)d_in[11];
    const float* be3 = (const float*)d_in[12];
    const float* w4  = (const float*)d_in[13];
    const float* b4  = (const float*)d_in[14];
    const float* g4  = (const float*)d_in[15];
    const float* be4 = (const float*)d_in[16];
    const float* w5  = (const float*)d_in[17];
    const float* b5  = (const float*)d_in[18];
    const float* g5  = (const float*)d_in[19];
    const float* be5 = (const float*)d_in[20];
    const float* w6  = (const float*)d_in[21];
    const float* b6  = (const float*)d_in[22];
    const float* g6  = (const float*)d_in[23];
    const float* be6 = (const float*)d_in[24];
    const float* fcw = (const float*)d_in[25];
    const float* fcb = (const float*)d_in[26];

    float* ws = (float*)d_ws;
    float* t1 = ws;                    // 64*128*128 = 1048576
    float* t2 = t1 + 64 * 128 * 128;   // 64*64*64   = 262144
    float* t3 = t2 + 64 * 64 * 64;     //              262144
    float* t4 = t3 + 64 * 64 * 64;     // 64*32*32   = 65536
    float* t5 = t4 + 64 * 32 * 32;     //              65536
    float* t6 = t5 + 64 * 32 * 32;     // 64*16*16   = 16384
    float* st = t6 + 64 * 16 * 16;     // 6 * 128 stats

    hipMemsetAsync(st, 0, 6 * 128 * sizeof(float), stream);

    // S1: x[128x128] --LC 7x7 p3--> t1[128x128]
    lc_stage<128, false, true,  7, 8><<<256, 256, 0, stream>>>(x,  nullptr,  nullptr, nullptr, w1, b1, t1, st + 0);
    // S2: LN1+pool -> 64x64 --LC 5x5 p2--> t2
    lc_stage<128, true,  false, 5, 4><<<256, 256, 0, stream>>>(t1, st + 0,   g1, be1, w2, b2, t2, st + 128);
    // S3: LN2 --LC 5x5 p2--> t3[64x64]
    lc_stage<64,  false, false, 5, 4><<<256, 256, 0, stream>>>(t2, st + 128, g2, be2, w3, b3, t3, st + 256);
    // S4: LN3+pool -> 32x32 --LC 3x3 p1--> t4
    lc_stage<64,  true,  false, 3, 4><<<64,  256, 0, stream>>>(t3, st + 256, g3, be3, w4, b4, t4, st + 384);
    // S5: LN4 --LC 3x3 p1--> t5[32x32]
    lc_stage<32,  false, false, 3, 4><<<64,  256, 0, stream>>>(t4, st + 384, g4, be4, w5, b5, t5, st + 512);
    // S6: LN5+pool -> 16x16 --LC 3x3 p1--> t6
    lc_stage<32,  true,  false, 3, 4><<<16,  256, 0, stream>>>(t5, st + 512, g5, be5, w6, b6, t6, st + 640);
    // FC + softmax
    fc_softmax<<<64, 256, 0, stream>>>(t6, st + 640, g6, be6, fcw, fcb, (float*)d_out);
}

// Round 2
// 184.265 us; speedup vs baseline: 1.2662x; 1.2662x over previous
//
#include <hip/hip_runtime.h>

#define LN_EPS 1e-5f

// ---------------------------------------------------------------------------
// Stage kernel: [optional LN(prev stats) + optional 2x2 maxpool] -> locally-
// connected conv + bias + ReLU -> raw output + per-sample (sum,sumsq) atomics.
//
// Block = TILE x TILE output tile  x  S samples (sample-split for occupancy).
// 256 threads: lane = (pg, s) with s = tid % S, pg = tid / S.
// Each thread computes OPT contiguous outputs in one row (register row reuse).
// ---------------------------------------------------------------------------
template<int RIN, bool POOL, bool FIRST, int K, int TILE, int S>
__launch_bounds__(256)
__global__ void lc_stage(const float* __restrict__ in,      // raw prev activations (or x)
                         const float* __restrict__ pstats,  // prev [sum(64), sumsq(64)]
                         const float* __restrict__ gamma,   // prev LN gamma [RIN*RIN]
                         const float* __restrict__ beta,    // prev LN beta  [RIN*RIN]
                         const float* __restrict__ w,       // [ROUT,ROUT,K,K]
                         const float* __restrict__ bias,    // [ROUT,ROUT]
                         float* __restrict__ out,           // raw this-stage [64,ROUT,ROUT]
                         float* __restrict__ stats)         // this [sum(64), sumsq(64)]
{
    constexpr int CIN  = POOL ? RIN / 2 : RIN;
    constexpr int ROUT = CIN;
    constexpr int PAD  = (K - 1) / 2;
    constexpr int RT   = TILE + K - 1;
    constexpr int PP   = RT * RT + 1;        // odd stride -> conflict-free
    constexpr int NBLK = ROUT / TILE;
    constexpr int WCNT = TILE * TILE * K * K;
    constexpr int SG   = 64 / S;             // sample groups
    constexpr int PG   = 256 / S;            // position groups
    constexpr int OPT  = (TILE * TILE >= PG) ? (TILE * TILE) / PG : 1;
    constexpr float INV_NPREV = 1.0f / (float)(RIN * RIN);

    struct WB { float w[WCNT]; float b[TILE * TILE]; };
    union UU { WB wb; float red[512]; };

    __shared__ float s_in[S * PP];
    __shared__ UU    s_u;
    __shared__ float s_mean[S], s_rstd[S];

    const int tid = threadIdx.x;
    const int bt  = blockIdx.x % (NBLK * NBLK);
    const int sg  = blockIdx.x / (NBLK * NBLK);
    const int i0  = (bt / NBLK) * TILE;
    const int j0  = (bt % NBLK) * TILE;
    const int S0  = sg * S;

    if constexpr (!FIRST) {
        if (tid < S) {
            float mu  = pstats[S0 + tid] * INV_NPREV;
            float msq = pstats[64 + S0 + tid] * INV_NPREV;
            s_mean[tid] = mu;
            s_rstd[tid] = 1.0f / sqrtf(msq - mu * mu + LN_EPS);
        }
        __syncthreads();
    }

    // --- stage weights + bias (tile-local, coalesced) ---
    for (int idx = tid; idx < WCNT; idx += 256) {
        int pi = idx / (K * K);
        int kk = idx % (K * K);
        int gi = i0 + pi / TILE, gj = j0 + pi % TILE;
        s_u.wb.w[idx] = w[(gi * ROUT + gj) * (K * K) + kk];
    }
    if (tid < TILE * TILE) {
        int gi = i0 + tid / TILE, gj = j0 + tid % TILE;
        s_u.wb.b[tid] = bias[gi * ROUT + gj];
    }

    // --- stage input region: LN (+pool) on the fly ---
    for (int idx = tid; idx < S * RT * RT; idx += 256) {
        int ls = idx / (RT * RT);
        int p  = idx % (RT * RT);
        int rr = p / RT, rc = p % RT;
        int ci = i0 - PAD + rr, cj = j0 - PAD + rc;
        float val = 0.0f;
        if (ci >= 0 && ci < CIN && cj >= 0 && cj < CIN) {
            if constexpr (FIRST) {
                val = in[(S0 + ls) * RIN * RIN + ci * RIN + cj];
            } else if constexpr (POOL) {
                float mu = s_mean[ls], rs = s_rstd[ls];
                float best = -3.4e38f;
                #pragma unroll
                for (int dy = 0; dy < 2; dy++) {
                    #pragma unroll
                    for (int dx = 0; dx < 2; dx++) {
                        int ry = 2 * ci + dy, rx = 2 * cj + dx;
                        float raw = in[(S0 + ls) * RIN * RIN + ry * RIN + rx];
                        float n = (raw - mu) * rs * gamma[ry * RIN + rx] + beta[ry * RIN + rx];
                        best = fmaxf(best, n);
                    }
                }
                val = best;
            } else {
                float mu = s_mean[ls], rs = s_rstd[ls];
                float raw = in[(S0 + ls) * RIN * RIN + ci * RIN + cj];
                val = (raw - mu) * rs * gamma[ci * RIN + cj] + beta[ci * RIN + cj];
            }
        }
        s_in[ls * PP + p] = val;
    }
    __syncthreads();

    // --- compute ---
    const int s  = tid % S;
    const int pg = tid / S;
    const int p0 = pg * OPT;
    float lsum = 0.0f, lsq = 0.0f;
    if (p0 < TILE * TILE) {
        const int ti  = p0 / TILE;
        const int tj0 = p0 % TILE;
        float acc[OPT];
        #pragma unroll
        for (int o = 0; o < OPT; o++) acc[o] = s_u.wb.b[p0 + o];
        #pragma unroll
        for (int ki = 0; ki < K; ki++) {
            float row[OPT + K - 1];
            #pragma unroll
            for (int c = 0; c < OPT + K - 1; c++)
                row[c] = s_in[s * PP + (ti + ki) * RT + tj0 + c];
            #pragma unroll
            for (int kj = 0; kj < K; kj++)
                #pragma unroll
                for (int o = 0; o < OPT; o++)
                    acc[o] += row[o + kj] * s_u.wb.w[(p0 + o) * (K * K) + ki * K + kj];
        }
        #pragma unroll
        for (int o = 0; o < OPT; o++) {
            float v = fmaxf(acc[o], 0.0f);
            out[(S0 + s) * ROUT * ROUT + (i0 + ti) * ROUT + (j0 + tj0 + o)] = v;
            lsum += v;
            lsq  += v * v;
        }
    }

    // --- per-sample LN-stat reduction, then atomics ---
    __syncthreads();                 // done with s_u.wb
    s_u.red[tid]       = lsum;
    s_u.red[256 + tid] = lsq;
    __syncthreads();
    if (tid < S) {
        float a = 0.0f, b = 0.0f;
        #pragma unroll
        for (int g = 0; g < PG; g++) {
            a += s_u.red[g * S + tid];
            b += s_u.red[256 + g * S + tid];
        }
        atomicAdd(&stats[S0 + tid], a);
        atomicAdd(&stats[64 + S0 + tid], b);
    }
}

// ---------------------------------------------------------------------------
// FC: LN6 -> flatten(256) -> logits[1024]. Block = (sample, quarter of rows).
// ---------------------------------------------------------------------------
__launch_bounds__(256)
__global__ void fc_logits(const float* __restrict__ t6,     // raw [64,16,16]
                          const float* __restrict__ stats6,
                          const float* __restrict__ g6,
                          const float* __restrict__ be6,
                          const float* __restrict__ fcw,    // [1024,256]
                          const float* __restrict__ fcb,
                          float* __restrict__ logits)       // [64,1024]
{
    __shared__ float h[256];
    const int s   = blockIdx.x >> 2;
    const int q   = blockIdx.x & 3;
    const int tid = threadIdx.x;

    float mu  = stats6[s] * (1.0f / 256.0f);
    float msq = stats6[64 + s] * (1.0f / 256.0f);
    float rstd = 1.0f / sqrtf(msq - mu * mu + LN_EPS);
    h[tid] = (t6[s * 256 + tid] - mu) * rstd * g6[tid] + be6[tid];
    __syncthreads();

    const int o = q * 256 + tid;
    const float4* wr = (const float4*)(fcw + o * 256);
    float acc = 0.0f;
    #pragma unroll 8
    for (int k = 0; k < 64; k++) {
        float4 wv = wr[k];
        acc += wv.x * h[4 * k] + wv.y * h[4 * k + 1] + wv.z * h[4 * k + 2] + wv.w * h[4 * k + 3];
    }
    logits[s * 1024 + o] = acc + fcb[o];
}

// ---------------------------------------------------------------------------
// Softmax over [64,1024]. One block per sample.
// ---------------------------------------------------------------------------
__launch_bounds__(256)
__global__ void softmax_k(const float* __restrict__ logits,
                          float* __restrict__ out)
{
    __shared__ float red[256];
    const int s   = blockIdx.x;
    const int tid = threadIdx.x;

    float4 v = ((const float4*)(logits + s * 1024))[tid];
    float lmax = fmaxf(fmaxf(v.x, v.y), fmaxf(v.z, v.w));
    red[tid] = lmax;
    __syncthreads();
    for (int off = 128; off > 0; off >>= 1) {
        if (tid < off) red[tid] = fmaxf(red[tid], red[tid + off]);
        __syncthreads();
    }
    float M = red[0];
    __syncthreads();

    float4 e;
    e.x = expf(v.x - M); e.y = expf(v.y - M);
    e.z = expf(v.z - M); e.w = expf(v.w - M);
    red[tid] = e.x + e.y + e.z + e.w;
    __syncthreads();
    for (int off = 128; off > 0; off >>= 1) {
        if (tid < off) red[tid] += red[tid + off];
        __syncthreads();
    }
    float inv = 1.0f / red[0];
    e.x *= inv; e.y *= inv; e.z *= inv; e.w *= inv;
    ((float4*)(out + s * 1024))[tid] = e;
}

// ---------------------------------------------------------------------------
extern "C" void kernel_launch(void* const* d_in, const int* in_sizes, int n_in,
                              void* d_out, int out_size, void* d_ws, size_t ws_size,
                              hipStream_t stream) {
    (void)in_sizes; (void)n_in; (void)out_size; (void)ws_size;

    const float* x   = (const float*)d_in[0];
    const float* w1  = (const float*)d_in[1];
    const float* b1  = (const float*)d_in[2];
    const float* g1  = (const float*)d_in[3];
    const float* be1 = (const float*)d_in[4];
    const float* w2  = (const float*)d_in[5];
    const float* b2  = (const float*)d_in[6];
    const float* g2  = (const float*)d_in[7];
    const float* be2 = (const float*)d_in[8];
    const float* w3  = (const float*)d_in[9];
    const float* b3  = (const float*)d_in[10];
    const float* g3  = (const float*)d_in[11];
    const float* be3 = (const float*)d_in[12];
    const float* w4  = (const float*)d_in[13];
    const float* b4  = (const float*)d_in[14];
    const float* g4  = (const float*)d_in[15];
    const float* be4 = (const float*)d_in[16];
    const float* w5  = (const float*)d_in[17];
    const float* b5  = (const float*)d_in[18];
    const float* g5  = (const float*)d_in[19];
    const float* be5 = (const float*)d_in[20];
    const float* w6  = (const float*)d_in[21];
    const float* b6  = (const float*)d_in[22];
    const float* g6  = (const float*)d_in[23];
    const float* be6 = (const float*)d_in[24];
    const float* fcw = (const float*)d_in[25];
    const float* fcb = (const float*)d_in[26];

    float* ws = (float*)d_ws;
    float* t1 = ws;                    // 64*128*128 = 1048576 (reused as logits later)
    float* t2 = t1 + 64 * 128 * 128;   // 64*64*64
    float* t3 = t2 + 64 * 64 * 64;
    float* t4 = t3 + 64 * 64 * 64;     // 64*32*32
    float* t5 = t4 + 64 * 32 * 32;
    float* t6 = t5 + 64 * 32 * 32;     // 64*16*16
    float* st = t6 + 64 * 16 * 16;     // 6 * 128 stats

    hipMemsetAsync(st, 0, 6 * 128 * sizeof(float), stream);

    // S1: x[128x128] --LC 7x7 p3--> t1[128x128]
    lc_stage<128, false, true,  7, 8, 16><<<1024, 256, 0, stream>>>(x,  nullptr,  nullptr, nullptr, w1, b1, t1, st + 0);
    // S2: LN1+pool -> 64x64 --LC 5x5 p2--> t2
    lc_stage<128, true,  false, 5, 4, 16><<<1024, 256, 0, stream>>>(t1, st + 0,   g1, be1, w2, b2, t2, st + 128);
    // S3: LN2 --LC 5x5 p2--> t3[64x64]
    lc_stage<64,  false, false, 5, 4, 16><<<1024, 256, 0, stream>>>(t2, st + 128, g2, be2, w3, b3, t3, st + 256);
    // S4: LN3+pool -> 32x32 --LC 3x3 p1--> t4
    lc_stage<64,  true,  false, 3, 4, 16><<<256,  256, 0, stream>>>(t3, st + 256, g3, be3, w4, b4, t4, st + 384);
    // S5: LN4 --LC 3x3 p1--> t5[32x32]
    lc_stage<32,  false, false, 3, 4, 16><<<256,  256, 0, stream>>>(t4, st + 384, g4, be4, w5, b5, t5, st + 512);
    // S6: LN5+pool -> 16x16 --LC 3x3 p1--> t6 (S=4 for more blocks)
    lc_stage<32,  true,  false, 3, 4, 4><<<256,   256, 0, stream>>>(t5, st + 512, g5, be5, w6, b6, t6, st + 640);
    // FC logits into t1 (dead by now), then softmax
    fc_logits<<<256, 256, 0, stream>>>(t6, st + 640, g6, be6, fcw, fcb, t1);
    softmax_k<<<64, 256, 0, stream>>>(t1, (float*)d_out);
}